// Round 2
// baseline (9615.021 us; speedup 1.0000x reference)
//
#include <hip/hip_runtime.h>
#include <hip/hip_bf16.h>
#include <stdint.h>

#define T_STEPS 100
#define BATCH   256
#define HDIM    2048
#define FDIM    720
#define M_ROWS  (T_STEPS * BATCH)      // 25600
#define TC      25                     // timesteps per chunk
#define MC      (TC * BATCH)           // 6400 rows per chunk
#define NCHUNK  (T_STEPS / TC)         // 4
#define BWORDS  64                     // u32 words per bit-row (2048 bits)

#define BM 128
#define BN 128
#define BKS 32                          // K-slab (bits per u32 word)
#define BNP 132                         // padded LDS leading dim (16B-aligned rows, breaks bank conflict)

// ---------------- pack binary fp32 input [M,720] -> bitmask [M, BWORDS u32]
__global__ __launch_bounds__(256)
void pack_x(const float* __restrict__ x, uint32_t* __restrict__ bits) {
    const int m = blockIdx.x;
    const int tid = threadIdx.x;
    const int lane = tid & 63;
    const float* row = x + (size_t)m * FDIM;
    unsigned long long* brow = (unsigned long long*)bits + (size_t)m * (BWORDS / 2);
#pragma unroll
    for (int it = 0; it < 3; ++it) {            // covers 768 bits (720 real + pad zeros)
        int h = it * 256 + tid;
        bool s = (h < FDIM) ? (row[h] >= 0.5f) : false;
        unsigned long long mask = __ballot(s);
        if (lane == 0) brow[(it * 256 + (tid & ~63)) >> 6] = mask;
    }
}

// ---------------- C[ml,h] = sum_k bitsA[row0+ml, k] * W[h,k] + bias[h]
// A is binary (bit-packed); W fp32 [HDIM, K] row-major. C is chunk-local [MC, HDIM].
template<int K>
__global__ __launch_bounds__(256)
void gemm_bits(const uint32_t* __restrict__ bits, const float* __restrict__ W,
               const float* __restrict__ bias, float* __restrict__ C, int row0) {
    __shared__ __align__(16) float Bs[BKS][BNP];
    const int n0  = blockIdx.x * BN;
    const int ml0 = blockIdx.y * BM;
    const int tid = threadIdx.x;
    const int tx  = tid & 15;          // 8 output columns each
    const int ty  = tid >> 4;          // 8 output rows each

    float acc[8][8] = {};
    constexpr int KS = (K + BKS - 1) / BKS;

    for (int s = 0; s < KS; ++s) {
        const int k0 = s * BKS;
        // stage W tile [32][128] (coalesced: consecutive lanes read consecutive k)
#pragma unroll
        for (int r = 0; r < 16; ++r) {
            int idx = tid + r * 256;           // 0..4095
            int j   = idx >> 5;                // 0..127
            int kk  = idx & 31;
            int k   = k0 + kk;
            Bs[kk][j] = (k < K) ? W[(size_t)(n0 + j) * K + k] : 0.0f;
        }
        // per-thread bit words for its 8 rows (tiny, L2-resident)
        uint32_t wA[8];
#pragma unroll
        for (int r = 0; r < 8; ++r) {
            int row = row0 + ml0 + ty * 8 + r;
            wA[r] = bits[(size_t)row * BWORDS + (k0 >> 5)];
        }
        __syncthreads();

#pragma unroll
        for (int kk = 0; kk < BKS; ++kk) {
            float bb[8];
#pragma unroll
            for (int c = 0; c < 8; c += 4) {
                float4 v = *reinterpret_cast<const float4*>(&Bs[kk][tx * 8 + c]);
                bb[c] = v.x; bb[c + 1] = v.y; bb[c + 2] = v.z; bb[c + 3] = v.w;
            }
#pragma unroll
            for (int r = 0; r < 8; ++r) {
                float af = ((wA[r] >> kk) & 1u) ? 1.0f : 0.0f;
#pragma unroll
                for (int c = 0; c < 8; ++c)
                    acc[r][c] = fmaf(af, bb[c], acc[r][c]);
            }
        }
        __syncthreads();
    }

    // epilogue: bias + float4 stores (C is chunk-local)
#pragma unroll
    for (int r = 0; r < 8; ++r) {
        size_t ml = (size_t)(ml0 + ty * 8 + r);
        float* Crow = C + ml * HDIM + n0 + tx * 8;
        const float* brow = bias + n0 + tx * 8;
#pragma unroll
        for (int c = 0; c < 8; c += 4) {
            float4 v;
            v.x = acc[r][c + 0] + brow[c + 0];
            v.y = acc[r][c + 1] + brow[c + 1];
            v.z = acc[r][c + 2] + brow[c + 2];
            v.w = acc[r][c + 3] + brow[c + 3];
            *reinterpret_cast<float4*>(Crow + c) = v;
        }
    }
}

// ---------------- reciprocal L2 norm per chunk-local row
__global__ __launch_bounds__(256)
void rnorm_chunk(const float* __restrict__ cur, float* __restrict__ rn) {
    const int row = blockIdx.x;
    const float* p = cur + (size_t)row * HDIM;
    float s = 0.f;
#pragma unroll
    for (int it = 0; it < HDIM / 1024; ++it) {
        float4 v = *reinterpret_cast<const float4*>(p + it * 1024 + threadIdx.x * 4);
        s += v.x * v.x + v.y * v.y + v.z * v.z + v.w * v.w;
    }
    __shared__ float red[256];
    red[threadIdx.x] = s;
    __syncthreads();
    for (int k = 128; k > 0; k >>= 1) {
        if (threadIdx.x < k) red[threadIdx.x] += red[threadIdx.x + k];
        __syncthreads();
    }
    if (threadIdx.x == 0) rn[row] = 1.0f / fmaxf(sqrtf(red[0]), 1e-12f);
}

// ---------------- LIF over one t-chunk; carries v & spike count across chunks
template<bool NORM, bool FIRST, bool LAST, bool WBITS>
__global__ __launch_bounds__(256)
void lif_chunk(const float* __restrict__ cur, const float* __restrict__ rn,
               uint32_t* __restrict__ obits, float* __restrict__ vstate,
               int* __restrict__ cnt, int row0) {
    const int b = blockIdx.y;
    const int h = blockIdx.x * 256 + threadIdx.x;
    const int lane = threadIdx.x & 63;
    const size_t bh = (size_t)b * HDIM + h;
    float v = FIRST ? 0.0f : vstate[bh];
    int   c_ = FIRST ? 0 : cnt[bh];
#pragma unroll 1
    for (int tl = 0; tl < TC; ++tl) {
        const int lrow = tl * BATCH + b;
        float c = cur[(size_t)lrow * HDIM + h];
        if (NORM) c *= rn[lrow];
        v = 0.5f * (v + c);
        bool s = (v >= 1.0f);
        if (WBITS) {
            unsigned long long mask = __ballot(s);
            if (lane == 0)
                ((unsigned long long*)obits)[(size_t)(row0 + lrow) * (BWORDS / 2) + (h >> 6)] = mask;
        }
        c_ += s ? 1 : 0;
        if (s) v = 0.0f;
    }
    if (!LAST) vstate[bh] = v;
    cnt[bh] = c_;
}

// ---------------- goodness[b] = mean_h (cnt/100)^2  (exact integer reduction)
__global__ __launch_bounds__(256)
void goodness(const int* __restrict__ cnt, float* __restrict__ out) {
    const int b = blockIdx.x;
    int s = 0;
    for (int j = threadIdx.x; j < HDIM; j += 256) {
        int c = cnt[(size_t)b * HDIM + j];
        s += c * c;
    }
    __shared__ int red[256];
    red[threadIdx.x] = s;
    __syncthreads();
    for (int k = 128; k > 0; k >>= 1) {
        if (threadIdx.x < k) red[threadIdx.x] += red[threadIdx.x + k];
        __syncthreads();
    }
    if (threadIdx.x == 0)
        out[b] = (float)red[0] * (1.0f / ((float)HDIM * 10000.0f));
}

// ---------------- host-side helpers
static inline void launch_lif_set(bool norm, bool wbits, int ck, const float* curc,
                                  const float* rn, uint32_t* obits, float* vst,
                                  int* cnt, hipStream_t stream) {
    dim3 g(HDIM / 256, BATCH);
    const int row0 = ck * MC;
    const bool first = (ck == 0), last = (ck == NCHUNK - 1);
#define LL(N, F, L, W) lif_chunk<N, F, L, W><<<g, 256, 0, stream>>>(curc, rn, obits, vst, cnt, row0)
    if (norm) {
        if (wbits) { if (first) { last ? LL(true,true,true,true)   : LL(true,true,false,true); }
                     else       { last ? LL(true,false,true,true)  : LL(true,false,false,true); } }
        else       { if (first) { last ? LL(true,true,true,false)  : LL(true,true,false,false); }
                     else       { last ? LL(true,false,true,false) : LL(true,false,false,false); } }
    } else {
        if (wbits) { if (first) { last ? LL(false,true,true,true)   : LL(false,true,false,true); }
                     else       { last ? LL(false,false,true,true)  : LL(false,false,false,true); } }
        else       { if (first) { last ? LL(false,true,true,false)  : LL(false,true,false,false); }
                     else       { last ? LL(false,false,true,false) : LL(false,false,false,false); } }
    }
#undef LL
}

extern "C" void kernel_launch(void* const* d_in, const int* in_sizes, int n_in,
                              void* d_out, int out_size, void* d_ws, size_t ws_size,
                              hipStream_t stream) {
    const float* x  = (const float*)d_in[0];
    const float* W0 = (const float*)d_in[1];
    const float* b0 = (const float*)d_in[2];
    const float* W1 = (const float*)d_in[3];
    const float* b1 = (const float*)d_in[4];
    const float* W2 = (const float*)d_in[5];
    const float* b2 = (const float*)d_in[6];
    float* out = (float*)d_out;

    char* ws = (char*)d_ws;
    size_t off = 0;
    float*    curc  = (float*)(ws + off);    off += (size_t)MC * HDIM * 4;       // 52.4 MB
    uint32_t* bitsA = (uint32_t*)(ws + off); off += (size_t)M_ROWS * BWORDS * 4; // 6.55 MB
    uint32_t* bitsB = (uint32_t*)(ws + off); off += (size_t)M_ROWS * BWORDS * 4; // 6.55 MB
    float*    rn    = (float*)(ws + off);    off += (size_t)MC * 4;              // 25.6 KB
    float*    vst   = (float*)(ws + off);    off += (size_t)BATCH * HDIM * 4;    // 2 MB
    int*      cnt   = (int*)(ws + off);      off += (size_t)BATCH * HDIM * 4;    // 2 MB
    // total ~= 69.6 MB

    pack_x<<<M_ROWS, 256, 0, stream>>>(x, bitsA);

    dim3 ggrid(HDIM / BN, MC / BM);   // (16, 50)

    // ---- layer 0: K=720, no norm, writes spike bits into bitsB
    for (int ck = 0; ck < NCHUNK; ++ck) {
        gemm_bits<FDIM><<<ggrid, 256, 0, stream>>>(bitsA, W0, b0, curc, ck * MC);
        launch_lif_set(false, true, ck, curc, rn, bitsB, vst, cnt, stream);
    }
    goodness<<<BATCH, 256, 0, stream>>>(cnt, out + 0);

    // ---- layer 1: K=2048, norm, writes spike bits into bitsA
    for (int ck = 0; ck < NCHUNK; ++ck) {
        gemm_bits<HDIM><<<ggrid, 256, 0, stream>>>(bitsB, W1, b1, curc, ck * MC);
        rnorm_chunk<<<MC, 256, 0, stream>>>(curc, rn);
        launch_lif_set(true, true, ck, curc, rn, bitsA, vst, cnt, stream);
    }
    goodness<<<BATCH, 256, 0, stream>>>(cnt, out + BATCH);

    // ---- layer 2: K=2048, norm, spikes not needed downstream
    for (int ck = 0; ck < NCHUNK; ++ck) {
        gemm_bits<HDIM><<<ggrid, 256, 0, stream>>>(bitsA, W2, b2, curc, ck * MC);
        rnorm_chunk<<<MC, 256, 0, stream>>>(curc, rn);
        launch_lif_set(true, false, ck, curc, rn, nullptr, vst, cnt, stream);
    }
    goodness<<<BATCH, 256, 0, stream>>>(cnt, out + 2 * BATCH);
}

// Round 3
// 1010.913 us; speedup vs baseline: 9.5112x; 9.5112x over previous
//
#include <hip/hip_runtime.h>
#include <hip/hip_bf16.h>
#include <stdint.h>

#define T_STEPS 100
#define BATCH   256
#define HDIM    2048
#define FDIM    720
#define KP0     736                      // FDIM padded to multiple of 32

typedef __hip_bfloat16 bf16;
typedef float f32x4 __attribute__((ext_vector_type(4)));
typedef short bf16x8 __attribute__((ext_vector_type(8)));

// ---------------- async global->LDS 16B
__device__ __forceinline__ void glds16(const bf16* g, bf16* l) {
    __builtin_amdgcn_global_load_lds(
        (const __attribute__((address_space(1))) void*)g,
        (__attribute__((address_space(3))) void*)l,
        16, 0, 0);
}

// ---------------- W fp32 [N,K] -> bf16 [N,KP] (zero-padded cols K..KP)
template<int K, int KP>
__global__ __launch_bounds__(256)
void cvt_w(const float* __restrict__ W, bf16* __restrict__ Wb) {
    int idx = blockIdx.x * 256 + threadIdx.x;       // over HDIM*KP
    int n = idx / KP, k = idx % KP;
    float w = (k < K) ? W[(size_t)n * K + k] : 0.0f;
    Wb[idx] = __float2bfloat16(w);
}

// ---------------- x fp32 chunk [MCr,720] -> bf16 [MCr,736] padded
__global__ __launch_bounds__(256)
void cvt_x(const float* __restrict__ x, bf16* __restrict__ xb, int row0) {
    int idx = blockIdx.x * 256 + threadIdx.x;       // over MCr*KP0
    int ml = idx / KP0, f = idx % KP0;
    float v = (f < FDIM) ? x[(size_t)(row0 + ml) * FDIM + f] : 0.0f;
    xb[idx] = __float2bfloat16(v);
}

// ---------------- C[m,n] = sum_k A[m,k]*B[n,k] + bias[n]
// A [M,KP] bf16 row-major, B [HDIM,KP] bf16 row-major, C [M,HDIM] fp32.
// 128x128 tile, BK=32, 4 waves (each 64x64), mfma_f32_16x16x32_bf16.
template<int KP>
__global__ __launch_bounds__(256)
void gemm_mfma(const bf16* __restrict__ A, const bf16* __restrict__ B,
               const float* __restrict__ bias, float* __restrict__ C) {
    __shared__ bf16 As[128 * 32];
    __shared__ bf16 Bs[128 * 32];
    const int tid  = threadIdx.x;
    const int lane = tid & 63;
    const int w    = tid >> 6;
    const int wr   = (w >> 1) * 64;      // wave row offset in 128-tile
    const int wc   = (w & 1) * 64;       // wave col offset
    const int m0   = blockIdx.y * 128;
    const int n0   = blockIdx.x * 128;
    const int fr   = lane & 15;          // fragment row (M/N index)
    const int fq   = lane >> 4;          // k-group

    f32x4 acc[4][4] = {};

    // staging addresses: thread covers 16B; 4 threads per 32-elem row
    const bf16* pA = A + (size_t)(m0 + (tid >> 2)) * KP + ((tid & 3) << 3);
    const bf16* pB = B + (size_t)(n0 + (tid >> 2)) * KP + ((tid & 3) << 3);
    bf16* dA0 = As + tid * 8;  bf16* dA1 = As + 2048 + tid * 8;
    bf16* dB0 = Bs + tid * 8;  bf16* dB1 = Bs + 2048 + tid * 8;
    const size_t rows64 = (size_t)64 * KP;

    for (int k0 = 0; k0 < KP; k0 += 32) {
        glds16(pA, dA0); glds16(pA + rows64, dA1);
        glds16(pB, dB0); glds16(pB + rows64, dB1);
        __syncthreads();                 // drains vmcnt + lgkm

        bf16x8 av[4], bv[4];
#pragma unroll
        for (int i = 0; i < 4; ++i) {
            av[i] = *(const bf16x8*)(As + (wr + i * 16 + fr) * 32 + fq * 8);
            bv[i] = *(const bf16x8*)(Bs + (wc + i * 16 + fr) * 32 + fq * 8);
        }
#pragma unroll
        for (int i = 0; i < 4; ++i)
#pragma unroll
            for (int j = 0; j < 4; ++j)
                acc[i][j] = __builtin_amdgcn_mfma_f32_16x16x32_bf16(
                    av[i], bv[j], acc[i][j], 0, 0, 0);
        __syncthreads();
        pA += 32; pB += 32;
    }

    // epilogue: C/D layout col=lane&15, row=(lane>>4)*4+reg  [verified m89/m91]
#pragma unroll
    for (int i = 0; i < 4; ++i) {
        const int rbase = m0 + wr + i * 16 + fq * 4;
#pragma unroll
        for (int j2 = 0; j2 < 4; ++j2) {
            float* Crow = C + (size_t)(rbase + j2) * HDIM + n0 + wc + fr;
#pragma unroll
            for (int jn = 0; jn < 4; ++jn)
                Crow[jn * 16] = acc[i][jn][j2] + bias[n0 + wc + jn * 16 + fr];
        }
    }
}

// ---------------- reciprocal L2 norm per chunk-local row
__global__ __launch_bounds__(256)
void rnorm_chunk(const float* __restrict__ cur, float* __restrict__ rn) {
    const int row = blockIdx.x;
    const float* p = cur + (size_t)row * HDIM;
    float s = 0.f;
#pragma unroll
    for (int it = 0; it < HDIM / 1024; ++it) {
        float4 v = *reinterpret_cast<const float4*>(p + it * 1024 + threadIdx.x * 4);
        s += v.x * v.x + v.y * v.y + v.z * v.z + v.w * v.w;
    }
    __shared__ float red[256];
    red[threadIdx.x] = s;
    __syncthreads();
    for (int k = 128; k > 0; k >>= 1) {
        if (threadIdx.x < k) red[threadIdx.x] += red[threadIdx.x + k];
        __syncthreads();
    }
    if (threadIdx.x == 0) rn[row] = 1.0f / fmaxf(sqrtf(red[0]), 1e-12f);
}

// ---------------- LIF over one t-chunk; v & count carry across chunks
template<bool NORM, bool FIRST, bool LAST, bool WSPK>
__global__ __launch_bounds__(256)
void lif_chunk(const float* __restrict__ cur, const float* __restrict__ rn,
               bf16* __restrict__ spk, float* __restrict__ vstate,
               int* __restrict__ cnt, int TCr) {
    const int b = blockIdx.y;
    const int h = blockIdx.x * 256 + threadIdx.x;
    const size_t bh = (size_t)b * HDIM + h;
    float v  = FIRST ? 0.0f : vstate[bh];
    int   c_ = FIRST ? 0 : cnt[bh];
    const bf16 one_b  = __float2bfloat16(1.0f);
    const bf16 zero_b = __float2bfloat16(0.0f);
#pragma unroll 1
    for (int tl = 0; tl < TCr; ++tl) {
        const int lrow = tl * BATCH + b;
        float c = cur[(size_t)lrow * HDIM + h];
        if (NORM) c *= rn[lrow];
        v = 0.5f * (v + c);
        bool s = (v >= 1.0f);
        if (WSPK) spk[(size_t)lrow * HDIM + h] = s ? one_b : zero_b;
        c_ += s ? 1 : 0;
        if (s) v = 0.0f;
    }
    if (!LAST) vstate[bh] = v;
    cnt[bh] = c_;
}

// ---------------- goodness[b] = mean_h (cnt/100)^2  (exact integers)
__global__ __launch_bounds__(256)
void goodness(const int* __restrict__ cnt, float* __restrict__ out) {
    const int b = blockIdx.x;
    int s = 0;
    for (int j = threadIdx.x; j < HDIM; j += 256) {
        int c = cnt[(size_t)b * HDIM + j];
        s += c * c;
    }
    __shared__ int red[256];
    red[threadIdx.x] = s;
    __syncthreads();
    for (int k = 128; k > 0; k >>= 1) {
        if (threadIdx.x < k) red[threadIdx.x] += red[threadIdx.x + k];
        __syncthreads();
    }
    if (threadIdx.x == 0)
        out[b] = (float)red[0] * (1.0f / ((float)HDIM * 10000.0f));
}

// ---------------- LIF launch dispatch
static inline void launch_lif(bool norm, bool wspk, bool first, bool last,
                              const float* cur, const float* rn, bf16* spk,
                              float* vst, int* cnt, int TCr, hipStream_t stream) {
    dim3 g(HDIM / 256, BATCH);
#define LL(N,F,L,W) lif_chunk<N,F,L,W><<<g,256,0,stream>>>(cur,rn,spk,vst,cnt,TCr)
    if (norm) {
        if (wspk) { if (first) { last?LL(true,true,true,true):LL(true,true,false,true); }
                    else       { last?LL(true,false,true,true):LL(true,false,false,true); } }
        else      { if (first) { last?LL(true,true,true,false):LL(true,true,false,false); }
                    else       { last?LL(true,false,true,false):LL(true,false,false,false); } }
    } else {
        if (wspk) { if (first) { last?LL(false,true,true,true):LL(false,true,false,true); }
                    else       { last?LL(false,false,true,true):LL(false,false,false,true); } }
        else      { if (first) { last?LL(false,true,true,false):LL(false,true,false,false); }
                    else       { last?LL(false,false,true,false):LL(false,false,false,false); } }
    }
#undef LL
}

extern "C" void kernel_launch(void* const* d_in, const int* in_sizes, int n_in,
                              void* d_out, int out_size, void* d_ws, size_t ws_size,
                              hipStream_t stream) {
    const float* x  = (const float*)d_in[0];
    const float* W0 = (const float*)d_in[1];
    const float* b0 = (const float*)d_in[2];
    const float* W1 = (const float*)d_in[3];
    const float* b1 = (const float*)d_in[4];
    const float* W2 = (const float*)d_in[5];
    const float* b2 = (const float*)d_in[6];
    float* out = (float*)d_out;

    // runtime chunk size from ws_size (deterministic: ws_size constant per process)
    int TCr;
    if      (ws_size >= 116500000ull) TCr = 20;   // needs 116.3 MB
    else if (ws_size >=  74500000ull) TCr = 10;   // needs  74.3 MB
    else                              TCr = 4;    // needs  49.2 MB
    const int nchunk = T_STEPS / TCr;
    const size_t MCr = (size_t)TCr * BATCH;

    char* p = (char*)d_ws;
    float* cur  = (float*)p;  p += MCr * HDIM * 4;
    bf16*  bufA = (bf16*)p;   p += MCr * HDIM * 2;
    bf16*  bufB = (bf16*)p;   p += MCr * HDIM * 2;
    bf16*  W0b  = (bf16*)p;   p += (size_t)HDIM * KP0 * 2;
    bf16*  W1b  = (bf16*)p;   p += (size_t)HDIM * HDIM * 2;
    bf16*  W2b  = (bf16*)p;   p += (size_t)HDIM * HDIM * 2;
    float* vst  = (float*)p;  p += 3 * (size_t)BATCH * HDIM * 4;
    int*   cnt  = (int*)p;    p += 3 * (size_t)BATCH * HDIM * 4;
    float* rn   = (float*)p;

    const size_t BH = (size_t)BATCH * HDIM;

    // one-time weight conversion (runs every launch; ~15 us)
    cvt_w<FDIM, KP0><<<HDIM * KP0 / 256, 256, 0, stream>>>(W0, W0b);
    cvt_w<HDIM, HDIM><<<HDIM * HDIM / 256, 256, 0, stream>>>(W1, W1b);
    cvt_w<HDIM, HDIM><<<HDIM * HDIM / 256, 256, 0, stream>>>(W2, W2b);

    dim3 ggrid(HDIM / 128, MCr / 128);

    for (int ck = 0; ck < nchunk; ++ck) {
        const bool first = (ck == 0), last = (ck == nchunk - 1);
        const int row0 = ck * TCr * BATCH;

        // layer 0: x chunk -> bf16 (padded), GEMM K=736, LIF (no norm)
        cvt_x<<<(int)(MCr * KP0 / 256), 256, 0, stream>>>(x, bufA, row0);
        gemm_mfma<KP0><<<ggrid, 256, 0, stream>>>(bufA, W0b, b0, cur);
        launch_lif(false, true, first, last, cur, rn, bufB, vst + 0 * BH, cnt + 0 * BH, TCr, stream);

        // layer 1: GEMM K=2048, norm, LIF
        gemm_mfma<HDIM><<<ggrid, 256, 0, stream>>>(bufB, W1b, b1, cur);
        rnorm_chunk<<<(int)MCr, 256, 0, stream>>>(cur, rn);
        launch_lif(true, true, first, last, cur, rn, bufA, vst + 1 * BH, cnt + 1 * BH, TCr, stream);

        // layer 2: GEMM K=2048, norm, LIF (no spike write)
        gemm_mfma<HDIM><<<ggrid, 256, 0, stream>>>(bufA, W2b, b2, cur);
        rnorm_chunk<<<(int)MCr, 256, 0, stream>>>(cur, rn);
        launch_lif(true, false, first, last, cur, rn, nullptr, vst + 2 * BH, cnt + 2 * BH, TCr, stream);
    }

    goodness<<<BATCH, 256, 0, stream>>>(cnt + 0 * BH, out + 0 * BATCH);
    goodness<<<BATCH, 256, 0, stream>>>(cnt + 1 * BH, out + 1 * BATCH);
    goodness<<<BATCH, 256, 0, stream>>>(cnt + 2 * BH, out + 2 * BATCH);
}

// Round 4
// 224.379 us; speedup vs baseline: 42.8517x; 4.5054x over previous
//
#include <hip/hip_runtime.h>
#include <hip/hip_bf16.h>
#include <stdint.h>

#define T_STEPS 100
#define BATCH   256
#define HDIM    2048
#define FDIM    720
#define KP0     736                      // FDIM padded to multiple of 32 (23 K-steps)
#define TCr     20                       // timesteps per chunk
#define MCr     (TCr * BATCH)            // 5120 rows per chunk
#define NCHUNK  (T_STEPS / TCr)          // 5

typedef __hip_bfloat16 bf16;
typedef float f32x4 __attribute__((ext_vector_type(4)));
typedef short bf16x8 __attribute__((ext_vector_type(8)));
typedef unsigned short u16x8 __attribute__((ext_vector_type(8)));

// NOTE (operator theorem): layers 1-2 L2-normalize currents, so every
// normalized element |c| <= 1. LIF: v' = (v+c)/2; spiking needs v' >= 1,
// i.e. c >= 2 - v > 1 while v < 1 (induction from v0=0). Therefore layers
// 1-2 NEVER spike for ANY input -> rate == 0 -> goodness == 0. Only layer 0
// must be computed; out[256:768] = 0.

// ---------------- async global->LDS 16B
__device__ __forceinline__ void glds16(const bf16* g, bf16* l) {
    __builtin_amdgcn_global_load_lds(
        (const __attribute__((address_space(1))) void*)g,
        (__attribute__((address_space(3))) void*)l,
        16, 0, 0);
}

// ---------------- W0 fp32 [2048,720] -> bf16 [2048,736] zero-padded
__global__ __launch_bounds__(256)
void cvt_w0(const float* __restrict__ W, bf16* __restrict__ Wb) {
    int idx = blockIdx.x * 256 + threadIdx.x;       // over HDIM*KP0
    int n = idx / KP0, k = idx % KP0;
    float w = (k < FDIM) ? W[(size_t)n * FDIM + k] : 0.0f;
    Wb[idx] = __float2bfloat16(w);
}

// ---------------- x fp32 [25600,720] -> bf16 [25600,736] padded, vectorized
// thread handles 8 consecutive cols; 92 threads per row (720 = 90*8, cols
// 720..735 are pad -> threads 90,91 of each row write zeros).
__global__ __launch_bounds__(256)
void cvt_x(const float* __restrict__ x, bf16* __restrict__ xb) {
    int idx = blockIdx.x * 256 + threadIdx.x;       // over 25600*92
    int row = idx / 92, c8 = (idx % 92) * 8;
    bf16 tmp[8];
    if (c8 < FDIM) {                                 // fully-real 8-col group
        const float* src = x + (size_t)row * FDIM + c8;
        float4 a = *reinterpret_cast<const float4*>(src);
        float4 b = *reinterpret_cast<const float4*>(src + 4);
        tmp[0] = __float2bfloat16(a.x); tmp[1] = __float2bfloat16(a.y);
        tmp[2] = __float2bfloat16(a.z); tmp[3] = __float2bfloat16(a.w);
        tmp[4] = __float2bfloat16(b.x); tmp[5] = __float2bfloat16(b.y);
        tmp[6] = __float2bfloat16(b.z); tmp[7] = __float2bfloat16(b.w);
    } else {
#pragma unroll
        for (int j = 0; j < 8; ++j) tmp[j] = __float2bfloat16(0.0f);
    }
    *reinterpret_cast<u16x8*>(xb + (size_t)row * KP0 + c8) =
        *reinterpret_cast<const u16x8*>(tmp);
}

// ---------------- C[m,n] = sum_k A[m,k]*B[n,k] + bias[n]
// A [*,KP0] bf16 row-major (chunk base pre-offset), B [HDIM,KP0] bf16,
// C [MCr,HDIM] fp32. 128x128 tile, BK=32, 4 waves, mfma 16x16x32 bf16.
__global__ __launch_bounds__(256)
void gemm_mfma(const bf16* __restrict__ A, const bf16* __restrict__ B,
               const float* __restrict__ bias, float* __restrict__ C) {
    __shared__ bf16 As[128 * 32];
    __shared__ bf16 Bs[128 * 32];
    const int tid  = threadIdx.x;
    const int lane = tid & 63;
    const int w    = tid >> 6;
    const int wr   = (w >> 1) * 64;
    const int wc   = (w & 1) * 64;
    const int m0   = blockIdx.y * 128;
    const int n0   = blockIdx.x * 128;
    const int fr   = lane & 15;
    const int fq   = lane >> 4;

    f32x4 acc[4][4] = {};

    const bf16* pA = A + (size_t)(m0 + (tid >> 2)) * KP0 + ((tid & 3) << 3);
    const bf16* pB = B + (size_t)(n0 + (tid >> 2)) * KP0 + ((tid & 3) << 3);
    bf16* dA0 = As + tid * 8;  bf16* dA1 = As + 2048 + tid * 8;
    bf16* dB0 = Bs + tid * 8;  bf16* dB1 = Bs + 2048 + tid * 8;
    const size_t rows64 = (size_t)64 * KP0;

    for (int k0 = 0; k0 < KP0; k0 += 32) {
        glds16(pA, dA0); glds16(pA + rows64, dA1);
        glds16(pB, dB0); glds16(pB + rows64, dB1);
        __syncthreads();

        bf16x8 av[4], bv[4];
#pragma unroll
        for (int i = 0; i < 4; ++i) {
            av[i] = *(const bf16x8*)(As + (wr + i * 16 + fr) * 32 + fq * 8);
            bv[i] = *(const bf16x8*)(Bs + (wc + i * 16 + fr) * 32 + fq * 8);
        }
#pragma unroll
        for (int i = 0; i < 4; ++i)
#pragma unroll
            for (int j = 0; j < 4; ++j)
                acc[i][j] = __builtin_amdgcn_mfma_f32_16x16x32_bf16(
                    av[i], bv[j], acc[i][j], 0, 0, 0);
        __syncthreads();
        pA += 32; pB += 32;
    }

    // C/D layout: col=lane&15, row=(lane>>4)*4+reg  [m89/m91]
#pragma unroll
    for (int i = 0; i < 4; ++i) {
        const int rbase = m0 + wr + i * 16 + fq * 4;
#pragma unroll
        for (int j2 = 0; j2 < 4; ++j2) {
            float* Crow = C + (size_t)(rbase + j2) * HDIM + n0 + wc + fr;
#pragma unroll
            for (int jn = 0; jn < 4; ++jn)
                Crow[jn * 16] = acc[i][jn][j2] + bias[n0 + wc + jn * 16 + fr];
        }
    }
}

// ---------------- layer-0 LIF over one t-chunk (no norm, no spike write)
template<bool FIRST, bool LAST>
__global__ __launch_bounds__(256)
void lif0(const float* __restrict__ cur, float* __restrict__ vstate,
          int* __restrict__ cnt) {
    const int b = blockIdx.y;
    const int h = blockIdx.x * 256 + threadIdx.x;
    const size_t bh = (size_t)b * HDIM + h;
    float v  = FIRST ? 0.0f : vstate[bh];
    int   c_ = FIRST ? 0 : cnt[bh];
#pragma unroll 1
    for (int tl = 0; tl < TCr; ++tl) {
        const int lrow = tl * BATCH + b;
        float c = cur[(size_t)lrow * HDIM + h];
        v = 0.5f * (v + c);
        bool s = (v >= 1.0f);
        c_ += s ? 1 : 0;
        if (s) v = 0.0f;
    }
    if (!LAST) vstate[bh] = v;
    cnt[bh] = c_;
}

// ---------------- goodness[b] = mean_h (cnt/100)^2  (exact integers)
__global__ __launch_bounds__(256)
void goodness(const int* __restrict__ cnt, float* __restrict__ out) {
    const int b = blockIdx.x;
    int s = 0;
    for (int j = threadIdx.x; j < HDIM; j += 256) {
        int c = cnt[(size_t)b * HDIM + j];
        s += c * c;
    }
    __shared__ int red[256];
    red[threadIdx.x] = s;
    __syncthreads();
    for (int k = 128; k > 0; k >>= 1) {
        if (threadIdx.x < k) red[threadIdx.x] += red[threadIdx.x + k];
        __syncthreads();
    }
    if (threadIdx.x == 0)
        out[b] = (float)red[0] * (1.0f / ((float)HDIM * 10000.0f));
}

extern "C" void kernel_launch(void* const* d_in, const int* in_sizes, int n_in,
                              void* d_out, int out_size, void* d_ws, size_t ws_size,
                              hipStream_t stream) {
    const float* x  = (const float*)d_in[0];
    const float* W0 = (const float*)d_in[1];
    const float* b0 = (const float*)d_in[2];
    float* out = (float*)d_out;

    char* p = (char*)d_ws;
    bf16*  xb  = (bf16*)p;   p += (size_t)25600 * KP0 * 2;          // 37.7 MB
    float* cur = (float*)p;  p += (size_t)MCr * HDIM * 4;           // 41.9 MB
    bf16*  W0b = (bf16*)p;   p += (size_t)HDIM * KP0 * 2;           //  3.0 MB
    float* vst = (float*)p;  p += (size_t)BATCH * HDIM * 4;         //  2.1 MB
    int*   cnt = (int*)p;                                           //  2.1 MB
    // total ~86.8 MB (< proven-available 116.5 MB)

    // layers 1-2 are identically zero (see theorem above)
    hipMemsetAsync(out + BATCH, 0, 2 * BATCH * sizeof(float), stream);

    cvt_w0<<<HDIM * KP0 / 256, 256, 0, stream>>>(W0, W0b);
    cvt_x<<<25600 * 92 / 256, 256, 0, stream>>>(x, xb);

    dim3 ggrid(HDIM / 128, MCr / 128);   // (16, 40)
    dim3 lgrid(HDIM / 256, BATCH);       // (8, 256)

    for (int ck = 0; ck < NCHUNK; ++ck) {
        const bf16* Ack = xb + (size_t)ck * MCr * KP0;
        gemm_mfma<<<ggrid, 256, 0, stream>>>(Ack, W0b, b0, cur);
        if (ck == 0)
            lif0<true, false><<<lgrid, 256, 0, stream>>>(cur, vst, cnt);
        else if (ck == NCHUNK - 1)
            lif0<false, true><<<lgrid, 256, 0, stream>>>(cur, vst, cnt);
        else
            lif0<false, false><<<lgrid, 256, 0, stream>>>(cur, vst, cnt);
    }
    goodness<<<BATCH, 256, 0, stream>>>(cnt, out);
}

// Round 5
// 200.781 us; speedup vs baseline: 47.8881x; 1.1175x over previous
//
#include <hip/hip_runtime.h>
#include <hip/hip_bf16.h>
#include <stdint.h>

#define T_STEPS 100
#define BATCH   256
#define HDIM    2048
#define FDIM    720
#define KP0     736                      // FDIM padded to 23*32
#define MROWS   (T_STEPS * BATCH)        // 25600

typedef __hip_bfloat16 bf16;
typedef float f32x4 __attribute__((ext_vector_type(4)));
typedef short bf16x8 __attribute__((ext_vector_type(8)));
typedef unsigned short u16x8 __attribute__((ext_vector_type(8)));

// Operator theorem (verified rounds 3-4, absmax 0.0): layers 1-2 L2-normalize
// currents => |c| <= 1; LIF v' = (v+c)/2 needs c > 1 to ever reach threshold
// from v < 1 (induction, v0=0) => layers 1-2 never spike => goodness == 0.
// Only layer 0 is computed; out[256:768] = 0.

__device__ __forceinline__ void glds16(const bf16* g, bf16* l) {
    __builtin_amdgcn_global_load_lds(
        (const __attribute__((address_space(1))) void*)g,
        (__attribute__((address_space(3))) void*)l,
        16, 0, 0);
}

// ---------------- W0 fp32 [2048,720] -> bf16 [2048,736] zero-padded
__global__ __launch_bounds__(256)
void cvt_w0(const float* __restrict__ W, bf16* __restrict__ Wb) {
    int idx = blockIdx.x * 256 + threadIdx.x;
    int n = idx / KP0, k = idx % KP0;
    float w = (k < FDIM) ? W[(size_t)n * FDIM + k] : 0.0f;
    Wb[idx] = __float2bfloat16(w);
}

// ---------------- x fp32 [25600,720] -> bf16 [25600,736] padded, vectorized
__global__ __launch_bounds__(256)
void cvt_x(const float* __restrict__ x, bf16* __restrict__ xb) {
    int idx = blockIdx.x * 256 + threadIdx.x;       // over 25600*92
    int row = idx / 92, c8 = (idx % 92) * 8;
    bf16 tmp[8];
    if (c8 < FDIM) {
        const float* src = x + (size_t)row * FDIM + c8;
        float4 a = *reinterpret_cast<const float4*>(src);
        float4 b = *reinterpret_cast<const float4*>(src + 4);
        tmp[0] = __float2bfloat16(a.x); tmp[1] = __float2bfloat16(a.y);
        tmp[2] = __float2bfloat16(a.z); tmp[3] = __float2bfloat16(a.w);
        tmp[4] = __float2bfloat16(b.x); tmp[5] = __float2bfloat16(b.y);
        tmp[6] = __float2bfloat16(b.z); tmp[7] = __float2bfloat16(b.w);
    } else {
#pragma unroll
        for (int j = 0; j < 8; ++j) tmp[j] = __float2bfloat16(0.0f);
    }
    *reinterpret_cast<u16x8*>(xb + (size_t)row * KP0 + c8) =
        *reinterpret_cast<const u16x8*>(tmp);
}

// ---------------- C[m,n] = sum_k A[m,k]*B[n,k] + bias[n]
// m97 structure: 128x128 tile, BK=32, 4 waves, mfma 16x16x32 bf16.
// XCD-chunked blockIdx swizzle (nwg % 8 == 0 in both call sites).
__global__ __launch_bounds__(256)
void gemm_mfma(const bf16* __restrict__ A, const bf16* __restrict__ B,
               const float* __restrict__ bias, float* __restrict__ C) {
    __shared__ bf16 As[128 * 32];
    __shared__ bf16 Bs[128 * 32];
    const int nwg  = gridDim.x * gridDim.y;
    const int flat = blockIdx.y * gridDim.x + blockIdx.x;
    const int swz  = (flat & 7) * (nwg >> 3) + (flat >> 3);
    const int bx   = swz & 15;                 // gridDim.x == 16 always
    const int by   = swz >> 4;
    const int tid  = threadIdx.x;
    const int lane = tid & 63;
    const int w    = tid >> 6;
    const int wr   = (w >> 1) * 64;
    const int wc   = (w & 1) * 64;
    const int m0   = by * 128;
    const int n0   = bx * 128;
    const int fr   = lane & 15;
    const int fq   = lane >> 4;

    f32x4 acc[4][4] = {};

    const bf16* pA = A + (size_t)(m0 + (tid >> 2)) * KP0 + ((tid & 3) << 3);
    const bf16* pB = B + (size_t)(n0 + (tid >> 2)) * KP0 + ((tid & 3) << 3);
    bf16* dA0 = As + tid * 8;  bf16* dA1 = As + 2048 + tid * 8;
    bf16* dB0 = Bs + tid * 8;  bf16* dB1 = Bs + 2048 + tid * 8;
    const size_t rows64 = (size_t)64 * KP0;

    for (int k0 = 0; k0 < KP0; k0 += 32) {
        glds16(pA, dA0); glds16(pA + rows64, dA1);
        glds16(pB, dB0); glds16(pB + rows64, dB1);
        __syncthreads();

        bf16x8 av[4], bv[4];
#pragma unroll
        for (int i = 0; i < 4; ++i) {
            av[i] = *(const bf16x8*)(As + (wr + i * 16 + fr) * 32 + fq * 8);
            bv[i] = *(const bf16x8*)(Bs + (wc + i * 16 + fr) * 32 + fq * 8);
        }
#pragma unroll
        for (int i = 0; i < 4; ++i)
#pragma unroll
            for (int j = 0; j < 4; ++j)
                acc[i][j] = __builtin_amdgcn_mfma_f32_16x16x32_bf16(
                    av[i], bv[j], acc[i][j], 0, 0, 0);
        __syncthreads();
        pA += 32; pB += 32;
    }

    // C/D layout: col=lane&15, row=(lane>>4)*4+reg
#pragma unroll
    for (int i = 0; i < 4; ++i) {
        const int rbase = m0 + wr + i * 16 + fq * 4;
#pragma unroll
        for (int j2 = 0; j2 < 4; ++j2) {
            float* Crow = C + (size_t)(rbase + j2) * HDIM + n0 + wc + fr;
#pragma unroll
            for (int jn = 0; jn < 4; ++jn)
                Crow[jn * 16] = acc[i][jn][j2] + bias[n0 + wc + jn * 16 + fr];
        }
    }
}

// ---------------- single-pass LIF over all T, fused exact goodness
// thread owns 4 consecutive h; v & counts in registers; integer atomics.
__global__ __launch_bounds__(256)
void lif_fused(const float* __restrict__ cur, int* __restrict__ gbuf) {
    const int b  = blockIdx.y;
    const int h4 = (blockIdx.x * 256 + threadIdx.x) * 4;
    const float* base = cur + (size_t)b * HDIM + h4;
    float v0 = 0.f, v1 = 0.f, v2 = 0.f, v3 = 0.f;
    int   c0 = 0, c1 = 0, c2 = 0, c3 = 0;
#pragma unroll 1
    for (int t = 0; t < T_STEPS; ++t) {
        float4 c = *reinterpret_cast<const float4*>(base + (size_t)t * BATCH * HDIM);
        v0 = 0.5f * (v0 + c.x); if (v0 >= 1.0f) { ++c0; v0 = 0.f; }
        v1 = 0.5f * (v1 + c.y); if (v1 >= 1.0f) { ++c1; v1 = 0.f; }
        v2 = 0.5f * (v2 + c.z); if (v2 >= 1.0f) { ++c2; v2 = 0.f; }
        v3 = 0.5f * (v3 + c.w); if (v3 >= 1.0f) { ++c3; v3 = 0.f; }
    }
    int g = c0 * c0 + c1 * c1 + c2 * c2 + c3 * c3;
    __shared__ int red[256];
    red[threadIdx.x] = g;
    __syncthreads();
    for (int k = 128; k > 0; k >>= 1) {
        if (threadIdx.x < k) red[threadIdx.x] += red[threadIdx.x + k];
        __syncthreads();
    }
    if (threadIdx.x == 0) atomicAdd(&gbuf[b], red[0]);
}

// ---------------- out[0:256] = gbuf*scale; out[256:768] = 0
__global__ __launch_bounds__(256)
void finalize(const int* __restrict__ gbuf, float* __restrict__ out) {
    int i = blockIdx.x * 256 + threadIdx.x;   // 0..767
    out[i] = (i < BATCH)
        ? (float)gbuf[i] * (1.0f / ((float)HDIM * 10000.0f))
        : 0.0f;
}

// ================ fallback (chunked, proven round 4) ================
#define TCF 20
#define MCF (TCF * BATCH)
template<bool FIRST, bool LAST>
__global__ __launch_bounds__(256)
void lif0(const float* __restrict__ cur, float* __restrict__ vstate,
          int* __restrict__ cnt) {
    const int b = blockIdx.y;
    const int h = blockIdx.x * 256 + threadIdx.x;
    const size_t bh = (size_t)b * HDIM + h;
    float v  = FIRST ? 0.0f : vstate[bh];
    int   c_ = FIRST ? 0 : cnt[bh];
#pragma unroll 1
    for (int tl = 0; tl < TCF; ++tl) {
        float c = cur[(size_t)(tl * BATCH + b) * HDIM + h];
        v = 0.5f * (v + c);
        bool s = (v >= 1.0f);
        c_ += s ? 1 : 0;
        if (s) v = 0.0f;
    }
    if (!LAST) vstate[bh] = v;
    cnt[bh] = c_;
}
__global__ __launch_bounds__(256)
void goodness(const int* __restrict__ cnt, float* __restrict__ out) {
    const int b = blockIdx.x;
    int s = 0;
    for (int j = threadIdx.x; j < HDIM; j += 256) {
        int c = cnt[(size_t)b * HDIM + j];
        s += c * c;
    }
    __shared__ int red[256];
    red[threadIdx.x] = s;
    __syncthreads();
    for (int k = 128; k > 0; k >>= 1) {
        if (threadIdx.x < k) red[threadIdx.x] += red[threadIdx.x + k];
        __syncthreads();
    }
    if (threadIdx.x == 0)
        out[b] = (float)red[0] * (1.0f / ((float)HDIM * 10000.0f));
}
__global__ __launch_bounds__(256)
void zero_tail(float* __restrict__ out) {
    int i = blockIdx.x * 256 + threadIdx.x;
    out[BATCH + i] = 0.0f;
}

extern "C" void kernel_launch(void* const* d_in, const int* in_sizes, int n_in,
                              void* d_out, int out_size, void* d_ws, size_t ws_size,
                              hipStream_t stream) {
    const float* x  = (const float*)d_in[0];
    const float* W0 = (const float*)d_in[1];
    const float* b0 = (const float*)d_in[2];
    float* out = (float*)d_out;

    const size_t XB_B  = (size_t)MROWS * KP0 * 2;        // 37,683,200
    const size_t W0B_B = (size_t)HDIM * KP0 * 2;         //  3,014,656

    if (ws_size >= XB_B + (size_t)MROWS * HDIM * 4 + W0B_B + 4096) {
        // ---------- single-chunk path (needs ~250.4 MB; observed ws ~281 MiB)
        char* p = (char*)d_ws;
        bf16*  xb   = (bf16*)p;   p += XB_B;
        float* cur  = (float*)p;  p += (size_t)MROWS * HDIM * 4;   // 209.7 MB
        bf16*  W0b  = (bf16*)p;   p += W0B_B;
        int*   gbuf = (int*)p;

        hipMemsetAsync(gbuf, 0, BATCH * sizeof(int), stream);
        cvt_w0<<<HDIM * KP0 / 256, 256, 0, stream>>>(W0, W0b);
        cvt_x<<<MROWS * 92 / 256, 256, 0, stream>>>(x, xb);

        dim3 ggrid(HDIM / 128, MROWS / 128);   // (16, 200), nwg=3200
        gemm_mfma<<<ggrid, 256, 0, stream>>>(xb, W0b, b0, cur);

        dim3 lgrid(HDIM / 1024, BATCH);        // (2, 256)
        lif_fused<<<lgrid, 256, 0, stream>>>(cur, gbuf);
        finalize<<<3, 256, 0, stream>>>(gbuf, out);
    } else {
        // ---------- fallback: 5-chunk path (needs ~86.8 MB; proven round 4)
        char* p = (char*)d_ws;
        bf16*  xb  = (bf16*)p;   p += XB_B;
        float* cur = (float*)p;  p += (size_t)MCF * HDIM * 4;
        bf16*  W0b = (bf16*)p;   p += W0B_B;
        float* vst = (float*)p;  p += (size_t)BATCH * HDIM * 4;
        int*   cnt = (int*)p;

        cvt_w0<<<HDIM * KP0 / 256, 256, 0, stream>>>(W0, W0b);
        cvt_x<<<MROWS * 92 / 256, 256, 0, stream>>>(x, xb);

        dim3 ggrid(HDIM / 128, MCF / 128);     // (16, 40), nwg=640
        dim3 lgrid(HDIM / 256, BATCH);
        for (int ck = 0; ck < T_STEPS / TCF; ++ck) {
            const bf16* Ack = xb + (size_t)ck * MCF * KP0;
            gemm_mfma<<<ggrid, 256, 0, stream>>>(Ack, W0b, b0, cur);
            if (ck == 0)                    lif0<true, false><<<lgrid, 256, 0, stream>>>(cur, vst, cnt);
            else if (ck == T_STEPS/TCF - 1) lif0<false, true><<<lgrid, 256, 0, stream>>>(cur, vst, cnt);
            else                            lif0<false, false><<<lgrid, 256, 0, stream>>>(cur, vst, cnt);
        }
        goodness<<<BATCH, 256, 0, stream>>>(cnt, out);
        zero_tail<<<2, 256, 0, stream>>>(out);
    }
}

// Round 6
// 128.675 us; speedup vs baseline: 74.7232x; 1.5604x over previous
//
#include <hip/hip_runtime.h>
#include <hip/hip_bf16.h>
#include <stdint.h>

#define T_STEPS 100
#define BATCH   256
#define HDIM    2048
#define FDIM    720
#define KP0     736                      // FDIM padded to 23*32
#define MROWS   (T_STEPS * BATCH)        // 25600

typedef __hip_bfloat16 bf16;
typedef float f32x4 __attribute__((ext_vector_type(4)));
typedef short bf16x8 __attribute__((ext_vector_type(8)));
typedef unsigned short u16x8 __attribute__((ext_vector_type(8)));

// Operator theorem (rounds 3-5, absmax 0.0): layers 1-2 L2-normalize currents
// => |c| <= 1; LIF v'=(v+c)/2 needs c>1 to reach threshold from v<1 => layers
// 1-2 never spike => goodness == 0. Only layer 0 is computed.

__device__ __forceinline__ void glds16(const bf16* g, bf16* l) {
    __builtin_amdgcn_global_load_lds(
        (const __attribute__((address_space(1))) void*)g,
        (__attribute__((address_space(3))) void*)l,
        16, 0, 0);
}

// ---------------- W0 fp32 [2048,720] -> bf16 [2048,736] zero-padded
__global__ __launch_bounds__(256)
void cvt_w0(const float* __restrict__ W, bf16* __restrict__ Wb) {
    int idx = blockIdx.x * 256 + threadIdx.x;
    int n = idx / KP0, k = idx % KP0;
    float w = (k < FDIM) ? W[(size_t)n * FDIM + k] : 0.0f;
    Wb[idx] = __float2bfloat16(w);
}

// ---------------- x fp32 [25600,720] -> bf16 [25600,736] padded, vectorized
__global__ __launch_bounds__(256)
void cvt_x(const float* __restrict__ x, bf16* __restrict__ xb) {
    int idx = blockIdx.x * 256 + threadIdx.x;       // over 25600*92
    int row = idx / 92, c8 = (idx % 92) * 8;
    bf16 tmp[8];
    if (c8 < FDIM) {
        const float* src = x + (size_t)row * FDIM + c8;
        float4 a = *reinterpret_cast<const float4*>(src);
        float4 b = *reinterpret_cast<const float4*>(src + 4);
        tmp[0] = __float2bfloat16(a.x); tmp[1] = __float2bfloat16(a.y);
        tmp[2] = __float2bfloat16(a.z); tmp[3] = __float2bfloat16(a.w);
        tmp[4] = __float2bfloat16(b.x); tmp[5] = __float2bfloat16(b.y);
        tmp[6] = __float2bfloat16(b.z); tmp[7] = __float2bfloat16(b.w);
    } else {
#pragma unroll
        for (int j = 0; j < 8; ++j) tmp[j] = __float2bfloat16(0.0f);
    }
    *reinterpret_cast<u16x8*>(xb + (size_t)row * KP0 + c8) =
        *reinterpret_cast<const u16x8*>(tmp);
}

// ---------------- fused layer-0: GEMM(tile per t) + LIF + goodness
// grid 256 = 8 b-blocks x 32 h-blocks; block tile 32(b) x 64(h); 8 waves:
// (mf 2) x (np 2) x (kh 2, K-split). B (W0 panel) in registers; A staged
// per-t via global_load_lds into XOR-swizzled LDS dbuf. v/cnt in registers.
#define A_ELE   (32 * KP0)               // 23552 elems per A buffer
#define A_BYTES (A_ELE * 2)              // 47104
#define LDS_BYTES (2 * A_BYTES + 2 * 512 * 4 * 4 + 128)  // 94208+16384+128

__global__ __launch_bounds__(512, 1)
void fused_l0(const bf16* __restrict__ xb, const bf16* __restrict__ Wb,
              const float* __restrict__ bias, int* __restrict__ gbuf) {
    extern __shared__ char smem[];
    bf16*  Ab0  = (bf16*)smem;                       // 2 x 23552 elems
    float* red  = (float*)(smem + 2 * A_BYTES);      // 2 x 2048 floats
    int*   gred = (int*)(smem + 2 * A_BYTES + 16384);

    const int tid  = threadIdx.x;
    const int lane = tid & 63, w = tid >> 6;
    const int mf = w & 1, np = (w >> 1) & 1, kh = w >> 2;
    const int fr = lane & 15, fq = lane >> 4;
    const int b0 = (blockIdx.x & 7) * 32;            // b-block -> XCD affinity
    const int n0 = (blockIdx.x >> 3) * 64;
    const int nst = kh ? 11 : 12;                    // K-split: 12 + 11 k-steps
    const int kb  = kh * 12;
    const int frq = fr & 7;

    // ---- B panel (W0) into registers: bv[nf][kk], nf in {0,1} (16 rows each)
    bf16x8 bv[2][12];
    {
        const bf16* wb0 = Wb + (size_t)(n0 + np * 32 + fr) * KP0 + fq * 8;
#pragma unroll
        for (int kk = 0; kk < 12; ++kk)
            if (kk < nst) {
                bv[0][kk] = *(const bf16x8*)(wb0 + (kb + kk) * 32);
                bv[1][kk] = *(const bf16x8*)(wb0 + (size_t)16 * KP0 + (kb + kk) * 32);
            }
    }
    const float bias_s = bias[n0 + np * 32 + kh * 16 + fr];
    if (tid < 32) gred[tid] = 0;

    f32x4 acc0 = {}, acc1 = {};
    float v[4]   = {0.f, 0.f, 0.f, 0.f};
    int   cnt[4] = {0, 0, 0, 0};

    // ---- A staging: 2944 slots of 16B; slot s -> row s/92, si s%92;
    // XOR-swizzle si^(row&7) for si<88 (involution, bank-conflict-minimal).
#define STAGE(T, P) do {                                                      \
        const size_t be_ = ((size_t)(T) * BATCH + b0) * KP0;                  \
        _Pragma("unroll")                                                     \
        for (int r_ = 0; r_ < 6; ++r_) {                                      \
            int s_ = r_ * 512 + tid;                                          \
            if (s_ < 2944) {                                                  \
                int row_ = s_ / 92, si_ = s_ - row_ * 92;                     \
                int g_ = (si_ < 88) ? (si_ ^ (row_ & 7)) : si_;               \
                glds16(xb + be_ + (size_t)row_ * KP0 + g_ * 8,                \
                       Ab0 + (P) * A_ELE + s_ * 8);                           \
            }                                                                 \
        }                                                                     \
    } while (0)

    STAGE(0, 0);
    __syncthreads();

    const int rowoff = (mf * 16 + fr) * KP0;
    int p = 0;
#pragma unroll 1
    for (int t = 0; t < T_STEPS; ++t) {
        if (t < T_STEPS - 1) STAGE(t + 1, p ^ 1);    // loads fly over compute

        const bf16* Ab = Ab0 + p * A_ELE;
#pragma unroll
        for (int kk = 0; kk < 12; ++kk)
            if (kk < nst) {
                int g = (kb + kk) * 4 + fq;
                int slot = (g < 88) ? (g ^ frq) : g;
                bf16x8 av = *(const bf16x8*)(Ab + rowoff + slot * 8);
                acc0 = __builtin_amdgcn_mfma_f32_16x16x32_bf16(av, bv[0][kk], acc0, 0, 0, 0);
                acc1 = __builtin_amdgcn_mfma_f32_16x16x32_bf16(av, bv[1][kk], acc1, 0, 0, 0);
            }

        // ---- K-split pair exchange (wave w <-> w^4), then in-register LIF
        const int par = t & 1;
        *(f32x4*)&red[par * 2048 + tid * 4] = kh ? acc0 : acc1;   // send
        __syncthreads();   // partials visible + A(t+1) staging drained
        f32x4 oth  = *(const f32x4*)&red[par * 2048 + (tid ^ 256) * 4];
        f32x4 mine = kh ? acc1 : acc0;
#pragma unroll
        for (int j = 0; j < 4; ++j) {
            float c = mine[j] + oth[j] + bias_s;
            v[j] = 0.5f * (v[j] + c);
            if (v[j] >= 1.0f) { cnt[j] += 1; v[j] = 0.0f; }
        }
        acc0 = (f32x4){}; acc1 = (f32x4){};
        p ^= 1;
    }
#undef STAGE

    // ---- exact integer goodness: block-local then global
#pragma unroll
    for (int j = 0; j < 4; ++j)
        atomicAdd(&gred[mf * 16 + fq * 4 + j], cnt[j] * cnt[j]);
    __syncthreads();
    if (tid < 32) atomicAdd(&gbuf[b0 + tid], gred[tid]);
}

// ---------------- out[0:256] = gbuf*scale; out[256:768] = 0 (theorem)
__global__ __launch_bounds__(256)
void finalize(const int* __restrict__ gbuf, float* __restrict__ out) {
    int i = blockIdx.x * 256 + threadIdx.x;   // 0..767
    out[i] = (i < BATCH)
        ? (float)gbuf[i] * (1.0f / ((float)HDIM * 10000.0f))
        : 0.0f;
}

extern "C" void kernel_launch(void* const* d_in, const int* in_sizes, int n_in,
                              void* d_out, int out_size, void* d_ws, size_t ws_size,
                              hipStream_t stream) {
    const float* x  = (const float*)d_in[0];
    const float* W0 = (const float*)d_in[1];
    const float* b0 = (const float*)d_in[2];
    float* out = (float*)d_out;

    // allow >64KB dynamic LDS (immediate runtime call, graph-capture safe)
    (void)hipFuncSetAttribute((const void*)fused_l0,
                              hipFuncAttributeMaxDynamicSharedMemorySize,
                              LDS_BYTES);

    char* p = (char*)d_ws;
    bf16* xb   = (bf16*)p;  p += (size_t)MROWS * KP0 * 2;   // 37.7 MB
    bf16* W0b  = (bf16*)p;  p += (size_t)HDIM * KP0 * 2;    //  3.0 MB
    int*  gbuf = (int*)p;                                   //  1 KB

    hipMemsetAsync(gbuf, 0, BATCH * sizeof(int), stream);
    cvt_w0<<<HDIM * KP0 / 256, 256, 0, stream>>>(W0, W0b);
    cvt_x<<<MROWS * 92 / 256, 256, 0, stream>>>(x, xb);

    fused_l0<<<256, 512, LDS_BYTES, stream>>>(xb, W0b, b0, gbuf);

    finalize<<<3, 256, 0, stream>>>(gbuf, out);
}